// Round 5
// baseline (6612.264 us; speedup 1.0000x reference)
//
#include <hip/hip_runtime.h>
#include <math.h>

#define HID   512
#define SEQL  256
#define BATCH 2048
#define NCLS  10
#define NBC   32     // batch columns per group (2 MFMA B-fragments wide)
#define NQ    4      // row-split ways: 4 WGs per group, each 128 j-rows x 4 gates
#define NGRP  (BATCH / NBC)          // 64 groups; grid = 64*4 = 256 WGs
#define HSTR  552    // padded f16 k-stride in LDS (bank rotation; 552*2B = 8B-mult)

typedef _Float16 f16x8 __attribute__((ext_vector_type(8)));
typedef _Float16 f16x4 __attribute__((ext_vector_type(4)));
typedef float    f32x4 __attribute__((ext_vector_type(4)));
typedef unsigned long long u64;

__device__ __forceinline__ float fsig(float v)  { return 1.f / (1.f + __expf(-v)); }
__device__ __forceinline__ float ftanh(float v) { return 1.f - 2.f / (1.f + __expf(2.f * v)); }

// Bounded acquire-spin (agent scope). Bounded so a protocol bug produces a
// visibly-wrong answer instead of a hung container.
__device__ __forceinline__ void spin_ge(int* p, int v) {
    for (int it = 0; it < (1 << 22); ++it) {
        if (__hip_atomic_load(p, __ATOMIC_ACQUIRE, __HIP_MEMORY_SCOPE_AGENT) >= v) return;
        __builtin_amdgcn_s_sleep(1);
    }
}

// Pack the 4 recurrent H x H matrices into per-(quarter,gate,tile,chunk) MFMA
// A-fragment blocks of 1 KiB: blk = ((q*4+g)*8 + p2)*16 + m; lane l holds 8 f16 =
// A[j = 128q+16p2+(l&15)][K = 32m+(l>>4)*8+v].  Total 2048 blocks = 2 MiB.
__global__ void pack_frags(const float* __restrict__ wg, const float* __restrict__ wi,
                           const float* __restrict__ wf, const float* __restrict__ wo,
                           f16x8* __restrict__ wq)
{
    const int idx = blockIdx.x * 256 + threadIdx.x;   // 512 blocks * 256 = 131072
    const int lane = idx & 63, blk = idx >> 6;
    const int m  = blk & 15;
    const int p2 = (blk >> 4) & 7;
    const int g  = (blk >> 7) & 3;
    const int q  = blk >> 9;
    const int j  = 128 * q + 16 * p2 + (lane & 15);
    const int k0 = 32 * m + (lane >> 4) * 8;
    const float* w = (g == 0) ? wg : (g == 1) ? wi : (g == 2) ? wf : wo;
    f16x8 vv;
    #pragma unroll
    for (int v = 0; v < 8; v++) vv[v] = (_Float16)w[j * HID + k0 + v];
    wq[blk * 64 + lane] = vv;
}

// Persistent 4-way row-split MFMA LSTM. 256 WGs (group G = bid>>2, quarter q = bid&3),
// 512 threads (8 waves). Wave wv owns row-tile p2=wv of each gate (4 A-frags/chunk).
// Per step: phase A = own K-quarter chunks (overlaps partner-flag wait), exchange
// partner h via IF (agent-scope atomics), phase B = remaining 12 chunks, nonlin,
// publish own h. Flags/acks live in this group's region of `out` (scratch until
// the epilogue overwrites it); ws = wq 2 MiB + xb 2 MiB = exactly 4 MiB.
__global__ __launch_bounds__(512, 1) void lstm_mfma(
    const float* __restrict__ x,                                   // [B][SEQ]
    const f16x8* __restrict__ wq,                                  // packed fragments
    const float* __restrict__ wgx, const float* __restrict__ wix,
    const float* __restrict__ wfx, const float* __restrict__ wox,  // [H]
    const float* __restrict__ bg,  const float* __restrict__ bi,
    const float* __restrict__ bf_, const float* __restrict__ bo,   // [H]
    const float* __restrict__ wph, const float* __restrict__ bp,   // [C][H], [C]
    const float* __restrict__ h_init, const float* __restrict__ c_init, // [H]
    u64* __restrict__ xb,                                          // [64][4][1024] u64
    float* __restrict__ out)                                       // [B][C] (+flags)
{
    __shared__ __align__(16) _Float16 hbuf[2][NBC][HSTR];  // 69 KB
    __shared__ float x_s[NBC][SEQL + 1];                   // 32.1 KB (pad: bank spread)

    const int tid  = threadIdx.x;
    const int lane = tid & 63;
    const int wv   = tid >> 6;          // wave 0..7 -> row-tile p2 = wv per gate
    const int col  = lane & 15;         // batch col within first B-fragment
    const int kq   = lane >> 4;
    const int G    = blockIdx.x >> 2;
    const int q    = blockIdx.x & 3;
    const int b0   = G * NBC;

    int* fl = (int*)out + G * (NBC * NCLS);   // group's 1280B region: ready fl[0..3], ack fl[16..19]

    for (int i = tid; i < NBC * SEQL; i += 512)
        x_s[i >> 8][i & 255] = x[(b0 + (i >> 8)) * SEQL + (i & 255)];

    // hbuf[0] = h_init broadcast (full K), hbuf[1] = 0; pads zero.
    for (int i = tid; i < 2 * NBC * HSTR; i += 512) {
        const int b = i / (NBC * HSTR), rem = i % (NBC * HSTR);
        const int k = rem % HSTR;
        ((_Float16*)hbuf)[i] = (_Float16)((b == 0 && k < HID) ? h_init[k] : 0.f);
    }

    // Per-thread row block: j = jg0..jg0+3 (same rows for all 4 gates).
    const int jg0 = 128 * q + 16 * wv + 4 * kq;
    f32x4 creg[2];
    creg[0] = *(const f32x4*)&c_init[jg0];
    creg[1] = creg[0];
    f32x4 wxv[4], bv[4];
    wxv[0] = *(const f32x4*)&wgx[jg0];  bv[0] = *(const f32x4*)&bg[jg0];
    wxv[1] = *(const f32x4*)&wix[jg0];  bv[1] = *(const f32x4*)&bi[jg0];
    wxv[2] = *(const f32x4*)&wfx[jg0];  bv[2] = *(const f32x4*)&bf_[jg0];
    wxv[3] = *(const f32x4*)&wox[jg0];  bv[3] = *(const f32x4*)&bo[jg0];

    int tofs[4];
    #pragma unroll
    for (int g = 0; g < 4; g++)
        tofs[g] = (((q * 4 + g) * 8 + wv) * 16) * 64 + lane;

    u64* myslot = xb + (G * 4 + q) * 1024;

    __syncthreads();

    #pragma unroll 1
    for (int t = 0; t < SEQL; t++) {
        const int rb = t & 1, wb = rb ^ 1;

        // acc init: wx*x_t + b  (x/bias not in the MFMA stream)
        f32x4 acc[4][2];
        #pragma unroll
        for (int ch = 0; ch < 2; ch++) {
            const float xv = x_s[col + 16 * ch][t];
            #pragma unroll
            for (int g = 0; g < 4; g++)
                #pragma unroll
                for (int r = 0; r < 4; r++)
                    acc[g][ch][r] = fmaf(wxv[g][r], xv, bv[g][r]);
        }

        // Phase A: own K-quarter (chunks (4q+c)&15, c=0..3) — h available locally.
        f16x8 A[2][4];
        {
            const int m0 = (4 * q) & 15;
            #pragma unroll
            for (int g = 0; g < 4; g++) A[0][g] = wq[tofs[g] + m0 * 64];
        }
        #pragma unroll
        for (int c = 0; c < 4; c++) {
            const int pb = c & 1;
            const int mn = (4 * q + c + 1) & 15;
            #pragma unroll
            for (int g = 0; g < 4; g++) A[pb ^ 1][g] = wq[tofs[g] + mn * 64];
            const int mc = (4 * q + c) & 15;
            const f16x8 B0 = *(const f16x8*)&hbuf[rb][col][mc * 32 + kq * 8];
            const f16x8 B1 = *(const f16x8*)&hbuf[rb][col + 16][mc * 32 + kq * 8];
            #pragma unroll
            for (int g = 0; g < 4; g++) {
                acc[g][0] = __builtin_amdgcn_mfma_f32_16x16x32_f16(A[pb][g], B0, acc[g][0], 0, 0, 0);
                acc[g][1] = __builtin_amdgcn_mfma_f32_16x16x32_f16(A[pb][g], B1, acc[g][1], 0, 0, 0);
            }
        }

        // Exchange-in: wait partner flags (overlapped with phase A), pull 3 quarters.
        if (t > 0 && tid < 3) spin_ge(&fl[(q + 1 + tid) & 3], t);
        __syncthreads();                                       // B1
        if (t > 0) {
            #pragma unroll
            for (int pp = 0; pp < 3; pp++) {
                const int pq = (q + 1 + pp) & 3;
                u64* ps = xb + (G * 4 + pq) * 1024;
                const int u = tid * 2;
                const u64 v0 = __hip_atomic_load(ps + u,     __ATOMIC_RELAXED, __HIP_MEMORY_SCOPE_AGENT);
                const u64 v1 = __hip_atomic_load(ps + u + 1, __ATOMIC_RELAXED, __HIP_MEMORY_SCOPE_AGENT);
                *(u64*)&hbuf[rb][u >> 5][128 * pq + 4 * (u & 31)]             = v0;
                *(u64*)&hbuf[rb][(u + 1) >> 5][128 * pq + 4 * ((u + 1) & 31)] = v1;
            }
        }
        __syncthreads();                                       // B2 (reads drained)
        if (t > 0 && tid < 3)
            __hip_atomic_fetch_add(&fl[16 + ((q + 1 + tid) & 3)], 1,
                                   __ATOMIC_RELAXED, __HIP_MEMORY_SCOPE_AGENT);

        // Phase B: remaining 12 chunks (A[0] already holds chunk c=4's frags).
        #pragma unroll
        for (int c = 4; c < 16; c++) {
            const int pb = c & 1;
            const int mn = (4 * q + c + 1) & 15;
            #pragma unroll
            for (int g = 0; g < 4; g++) A[pb ^ 1][g] = wq[tofs[g] + mn * 64];
            const int mc = (4 * q + c) & 15;
            const f16x8 B0 = *(const f16x8*)&hbuf[rb][col][mc * 32 + kq * 8];
            const f16x8 B1 = *(const f16x8*)&hbuf[rb][col + 16][mc * 32 + kq * 8];
            #pragma unroll
            for (int g = 0; g < 4; g++) {
                acc[g][0] = __builtin_amdgcn_mfma_f32_16x16x32_f16(A[pb][g], B0, acc[g][0], 0, 0, 0);
                acc[g][1] = __builtin_amdgcn_mfma_f32_16x16x32_f16(A[pb][g], B1, acc[g][1], 0, 0, 0);
            }
        }

        // Nonlinearity + own-h LDS write; keep packed u64 for publish.
        u64 hv64[2];
        #pragma unroll
        for (int ch = 0; ch < 2; ch++) {
            f16x4 hv;
            #pragma unroll
            for (int r = 0; r < 4; r++) {
                const float cc = ftanh(acc[0][ch][r]) * fsig(acc[1][ch][r])
                               + creg[ch][r] * fsig(acc[2][ch][r]);
                creg[ch][r] = cc;
                hv[r] = (_Float16)(ftanh(cc) * fsig(acc[3][ch][r]));
            }
            *(f16x4*)&hbuf[wb][col + 16 * ch][jg0] = hv;
            hv64[ch] = __builtin_bit_cast(u64, hv);
        }

        // Publish: wait all 3 readers consumed version t, then store version t+1.
        if (t > 0 && tid == 0) spin_ge(&fl[16 + q], 3 * t);
        __syncthreads();                                       // B3
        #pragma unroll
        for (int ch = 0; ch < 2; ch++)
            __hip_atomic_store(myslot + ((col + 16 * ch) * 32 + 4 * wv + kq), hv64[ch],
                               __ATOMIC_RELAXED, __HIP_MEMORY_SCOPE_AGENT);
        __syncthreads();                                       // B4 (vmcnt drained)
        if (tid == 0)
            __hip_atomic_store(&fl[q], t + 1, __ATOMIC_RELEASE, __HIP_MEMORY_SCOPE_AGENT);
    }

    // Epilogue (q==0 only): gather final h (version 256), overwrite flags with output.
    if (q == 0) {
        if (tid < 3) spin_ge(&fl[(1 + tid) & 3], SEQL);
        __syncthreads();
        #pragma unroll
        for (int pp = 0; pp < 3; pp++) {
            const int pq = 1 + pp;
            u64* ps = xb + (G * 4 + pq) * 1024;
            const int u = tid * 2;
            const u64 v0 = __hip_atomic_load(ps + u,     __ATOMIC_RELAXED, __HIP_MEMORY_SCOPE_AGENT);
            const u64 v1 = __hip_atomic_load(ps + u + 1, __ATOMIC_RELAXED, __HIP_MEMORY_SCOPE_AGENT);
            *(u64*)&hbuf[0][u >> 5][128 * pq + 4 * (u & 31)]             = v0;
            *(u64*)&hbuf[0][(u + 1) >> 5][128 * pq + 4 * ((u + 1) & 31)] = v1;
        }
        __syncthreads();
        if (tid < NBC * NCLS) {
            const int c = tid / NCLS, cls = tid - c * NCLS;
            float s = bp[cls];
            for (int k = 0; k < HID; k++)
                s = fmaf(wph[cls * HID + k], (float)hbuf[0][c][k], s);
            out[(b0 + c) * NCLS + cls] = s;
        }
    }
}

extern "C" void kernel_launch(void* const* d_in, const int* in_sizes, int n_in,
                              void* d_out, int out_size, void* d_ws, size_t ws_size,
                              hipStream_t stream)
{
    const float* x   = (const float*)d_in[0];
    const float* wgx = (const float*)d_in[1];
    const float* wix = (const float*)d_in[2];
    const float* wfx = (const float*)d_in[3];
    const float* wox = (const float*)d_in[4];
    const float* wgh = (const float*)d_in[5];
    const float* wih = (const float*)d_in[6];
    const float* wfh = (const float*)d_in[7];
    const float* woh = (const float*)d_in[8];
    const float* bg  = (const float*)d_in[9];
    const float* bi  = (const float*)d_in[10];
    const float* bf  = (const float*)d_in[11];
    const float* bo  = (const float*)d_in[12];
    const float* wph = (const float*)d_in[13];
    const float* bp  = (const float*)d_in[14];
    const float* h0  = (const float*)d_in[15];
    const float* c0  = (const float*)d_in[16];
    float* out = (float*)d_out;
    f16x8* wq = (f16x8*)d_ws;                              // 2 MiB packed fragments
    u64*   xb = (u64*)((char*)d_ws + (2u << 20));          // 2 MiB exchange slots

    // Zero flags/acks (they live in `out`, which is scratch until the epilogue).
    hipMemsetAsync(out, 0, BATCH * NCLS * sizeof(float), stream);
    pack_frags<<<dim3(512), dim3(256), 0, stream>>>(wgh, wih, wfh, woh, wq);
    lstm_mfma<<<dim3(NGRP * NQ), dim3(512), 0, stream>>>(
        x, wq, wgx, wix, wfx, wox, bg, bi, bf, bo, wph, bp, h0, c0, xb, out);
}

// Round 6
// 4932.032 us; speedup vs baseline: 1.3407x; 1.3407x over previous
//
#include <hip/hip_runtime.h>
#include <math.h>

#define HID   512
#define SEQL  256
#define BATCH 2048
#define NCLS  10
#define NB    16     // batch columns per WG = full MFMA tile width
#define H16S  552    // f16 elems per LDS h-row (512 + seed 4 + pad); 1104 B, 16B-mult
#define H8S   552    // bytes per LDS fp8 h-row (512 + pad); 8B-mult, bank-spread

typedef _Float16 f16x8 __attribute__((ext_vector_type(8)));
typedef _Float16 f16x4 __attribute__((ext_vector_type(4)));
typedef _Float16 f16x2 __attribute__((ext_vector_type(2)));
typedef float    f32x4 __attribute__((ext_vector_type(4)));
typedef long     i64;

__device__ __forceinline__ float fsig(float v)  { return 1.f / (1.f + __expf(-v)); }
__device__ __forceinline__ float ftanh(float v) { return 1.f - 2.f / (1.f + __expf(2.f * v)); }

// ---- pack g-gate f16 main frags + per-gate seed (wx,b) table -------------
// wq16[(p*16+m)*64+lane] : f16x8 = wgh[j=16p+(l&15)][k=32m+(l>>4)*8+v]
// seedw[gt*512 + p*16 + r] : f16x2 {wx*sc, b*sc}, sc = (gt==0 ? 1 : 16384)
__global__ void pack16(const float* __restrict__ wgh,
                       const float* __restrict__ wgx, const float* __restrict__ wix,
                       const float* __restrict__ wfx, const float* __restrict__ wox,
                       const float* __restrict__ bg,  const float* __restrict__ bi,
                       const float* __restrict__ bf_, const float* __restrict__ bo,
                       f16x8* __restrict__ wq16, unsigned* __restrict__ seedw)
{
    const int idx = blockIdx.x * 256 + threadIdx.x;
    if (idx < 32768) {
        const int lane = idx & 63, blk = idx >> 6;
        const int m = blk & 15, p = blk >> 4;
        const int j = 16 * p + (lane & 15), k0 = 32 * m + (lane >> 4) * 8;
        f16x8 v;
        #pragma unroll
        for (int t = 0; t < 8; t++) v[t] = (_Float16)wgh[j * HID + k0 + t];
        wq16[blk * 64 + lane] = v;
    } else if (idx < 32768 + 2048) {
        const int s = idx - 32768;
        const int r = s & 15, p = (s >> 4) & 31, gt = s >> 9;
        const int j = 16 * p + r;
        const float wx = (gt == 0 ? wgx : gt == 1 ? wix : gt == 2 ? wfx : wox)[j];
        const float bb = (gt == 0 ? bg  : gt == 1 ? bi  : gt == 2 ? bf_ : bo)[j];
        const float sc = (gt == 0) ? 1.f : 16384.f;
        f16x2 pr; pr[0] = (_Float16)(wx * sc); pr[1] = (_Float16)(bb * sc);
        seedw[s] = __builtin_bit_cast(unsigned, pr);
    }
}

// ---- pack i/f/o fp8 frags, weights scaled x128 (e4m3 denormal floor) ----
// wq8[((gt*32+p)*16+m)*64+lane] : 8 bytes = fp8(w[j][32m+(l>>4)*8+v] * 128)
__global__ void pack8(const float* __restrict__ wih, const float* __restrict__ wfh,
                      const float* __restrict__ woh, uint2* __restrict__ wq8)
{
    const int idx = blockIdx.x * 256 + threadIdx.x;   // 98304 total
    const int lane = idx & 63, m = (idx >> 6) & 15, p = (idx >> 10) & 31, gt = idx >> 15;
    if (gt >= 3) return;
    const float* w = (gt == 0) ? wih : (gt == 1) ? wfh : woh;
    const int j = 16 * p + (lane & 15), k0 = 32 * m + (lane >> 4) * 8;
    float v[8];
    #pragma unroll
    for (int t = 0; t < 8; t++) v[t] = w[j * HID + k0 + t] * 128.f;
    int lo = __builtin_amdgcn_cvt_pk_fp8_f32(v[0], v[1], 0, false);
    lo     = __builtin_amdgcn_cvt_pk_fp8_f32(v[2], v[3], lo, true);
    int hi = __builtin_amdgcn_cvt_pk_fp8_f32(v[4], v[5], 0, false);
    hi     = __builtin_amdgcn_cvt_pk_fp8_f32(v[6], v[7], hi, true);
    wq8[((gt * 32 + p) * 16 + m) * 64 + lane] = make_uint2((unsigned)lo, (unsigned)hi);
}

// ---- persistent MFMA LSTM, R4 skeleton + fp8 i/f/o ----------------------
// 128 WGs x 512 thr (8 waves, 1 WG/CU). Wave wv owns row-tiles p = wv+8*pi.
// g: f16 MFMA (unscaled). i/f/o: fp8 MFMA, acc holds preact*16384 (w*128, h*128),
// un-scaled by one exact pow2 mul at nonlin. x/bias enter via a f16 seed MFMA
// (B cols k=512:x, k=513:1; ifo seed A pre-scaled *16384).
#define CHUNK(GBUF, QBUF, MM)                                                         \
  {                                                                                   \
    const f16x8 B16 = *(const f16x8*)&hbuf16[rb][col][(MM) * 32 + kq * 8];            \
    const i64   B8  = *(const i64*)&h8s[rb][col * H8S + (MM) * 32 + kq * 8];          \
    _Pragma("unroll")                                                                 \
    for (int pi = 0; pi < 4; pi++)                                                    \
      acc[0][pi] = __builtin_amdgcn_mfma_f32_16x16x32_f16(GBUF[pi], B16, acc[0][pi], 0, 0, 0); \
    _Pragma("unroll")                                                                 \
    for (int gt = 1; gt < 4; gt++)                                                    \
      _Pragma("unroll")                                                               \
      for (int pi = 0; pi < 4; pi++)                                                  \
        acc[gt][pi] = __builtin_amdgcn_mfma_f32_16x16x32_fp8_fp8(                     \
            QBUF[(gt - 1) * 4 + pi], B8, acc[gt][pi], 0, 0, 0);                       \
  }
#define PREF_G(GBUF, MM)                                                              \
  _Pragma("unroll")                                                                   \
  for (int pi = 0; pi < 4; pi++) GBUF[pi] = wq16[vo + pi * 8192 + (MM) * 64];
#define PREF_Q(QBUF, MM)                                                              \
  _Pragma("unroll")                                                                   \
  for (int gt = 0; gt < 3; gt++)                                                      \
    _Pragma("unroll")                                                                 \
    for (int pi = 0; pi < 4; pi++)                                                    \
      QBUF[gt * 4 + pi] = wq8[vo + gt * 32768 + pi * 8192 + (MM) * 64];

__global__ __launch_bounds__(512, 1) void lstm_mfma(
    const float* __restrict__ x,                                   // [B][SEQ]
    const f16x8* __restrict__ wq16, const unsigned* __restrict__ seedw,
    const i64*   __restrict__ wq8,
    const float* __restrict__ wph, const float* __restrict__ bp,   // [C][H], [C]
    const float* __restrict__ h_init, const float* __restrict__ c_init, // [H]
    float* __restrict__ out)                                       // [B][C]
{
    __shared__ __align__(16) _Float16 hbuf16[2][NB][H16S];  // 34.5 KB
    __shared__ __align__(8)  char     h8s[2][NB * H8S];     // 17.3 KB
    __shared__ float x_s[NB][SEQL + 1];                     // 16.4 KB

    const int tid  = threadIdx.x;
    const int lane = tid & 63;
    const int wv   = tid >> 6;
    const int col  = lane & 15;
    const int kq   = lane >> 4;
    const int b0   = blockIdx.x * NB;
    const int vo   = wv * 1024 + lane;   // shared lane-voffset for wq16 & wq8

    for (int i = tid; i < NB * SEQL; i += 512)
        x_s[i >> 8][i & 255] = x[(b0 + (i >> 8)) * SEQL + (i & 255)];
    __syncthreads();   // x_s ready (needed for hbuf16 seed init)

    for (int i = tid; i < 2 * NB * H16S; i += 512) {
        const int b = i / (NB * H16S), rem = i % (NB * H16S);
        const int c = rem / H16S, k = rem % H16S;
        float v = 0.f;
        if (b == 0) {
            if (k < HID)           v = h_init[k];
            else if (k == HID)     v = x_s[c][0];
            else if (k == HID + 1) v = 1.f;
        }
        ((_Float16*)hbuf16)[i] = (_Float16)v;
    }
    for (int i = tid; i < 2 * NB * H8S; i += 512) {
        const int b = i / (NB * H8S), k = (i % (NB * H8S)) % H8S;
        float v = (b == 0 && k < HID) ? h_init[k] * 128.f : 0.f;
        const int pk = __builtin_amdgcn_cvt_pk_fp8_f32(v, 0.f, 0, false);
        ((char*)h8s)[i] = (char)(pk & 0xff);
    }

    const int j00 = 16 * wv + 4 * kq;   // pi=0 row base; pi adds 128
    f32x4 creg[4];
    #pragma unroll
    for (int pi = 0; pi < 4; pi++) creg[pi] = *(const f32x4*)&c_init[j00 + 128 * pi];

    unsigned sv[4][4];  // seed (wx,b) f16 pairs; only kq==0 lanes carry data
    #pragma unroll
    for (int gt = 0; gt < 4; gt++)
        #pragma unroll
        for (int pi = 0; pi < 4; pi++)
            sv[gt][pi] = (kq == 0) ? seedw[gt * 512 + (wv + 8 * pi) * 16 + col] : 0u;

    __syncthreads();

    #pragma unroll 1
    for (int t = 0; t < SEQL; t++) {
        const int rb = t & 1, wb = rb ^ 1;

        f32x4 acc[4][4];
        #pragma unroll
        for (int gt = 0; gt < 4; gt++)
            #pragma unroll
            for (int pi = 0; pi < 4; pi++)
                acc[gt][pi] = (f32x4){0.f, 0.f, 0.f, 0.f};

        f16x8 G0[4], G1[4];
        i64   Q0[12], Q1[12];
        PREF_G(G0, 0); PREF_Q(Q0, 0);

        #pragma unroll 1
        for (int mp = 0; mp < 8; mp++) {
            const int m0 = 2 * mp, m1 = 2 * mp + 1;
            const int m2 = (m1 + 1 < 16) ? m1 + 1 : 15;   // clamped (tail reload ok)
            PREF_G(G1, m1); PREF_Q(Q1, m1);
            CHUNK(G0, Q0, m0);
            PREF_G(G0, m2); PREF_Q(Q0, m2);
            CHUNK(G1, Q1, m1);
        }

        // Seed MFMA: B cols k=512 (x_t), k=513 (1). g A=(wx,b); ifo A=(wx,b)*16384.
        {
            const f16x8 Bs = *(const f16x8*)&hbuf16[rb][col][512 + kq * 8];
            #pragma unroll
            for (int gt = 0; gt < 4; gt++)
                #pragma unroll
                for (int pi = 0; pi < 4; pi++) {
                    const f16x2 pr = __builtin_bit_cast(f16x2, sv[gt][pi]);
                    f16x8 F = {};
                    F[0] = pr[0]; F[1] = pr[1];
                    acc[gt][pi] = __builtin_amdgcn_mfma_f32_16x16x32_f16(F, Bs, acc[gt][pi], 0, 0, 0);
                }
        }

        // Nonlinearity; ifo accs carry preact*16384.
        const float S2I = 1.f / 16384.f;
        #pragma unroll
        for (int pi = 0; pi < 4; pi++) {
            const int j0 = j00 + 128 * pi;
            f16x4 hv16;
            float hq[4];
            #pragma unroll
            for (int r = 0; r < 4; r++) {
                const float g  = ftanh(acc[0][pi][r]);
                const float ii = fsig(acc[1][pi][r] * S2I);
                const float ff = fsig(acc[2][pi][r] * S2I);
                const float oo = fsig(acc[3][pi][r] * S2I);
                const float cc = fmaf(g, ii, creg[pi][r] * ff);
                creg[pi][r] = cc;
                const float h = ftanh(cc) * oo;
                hv16[r] = (_Float16)h;
                hq[r]   = h * 128.f;
            }
            *(f16x4*)&hbuf16[wb][col][j0] = hv16;
            int pk = __builtin_amdgcn_cvt_pk_fp8_f32(hq[0], hq[1], 0, false);
            pk     = __builtin_amdgcn_cvt_pk_fp8_f32(hq[2], hq[3], pk, true);
            *(unsigned*)&h8s[wb][col * H8S + j0] = (unsigned)pk;
        }
        if (tid < NB) {
            const int tn = (t + 1 < SEQL) ? t + 1 : t;
            hbuf16[wb][tid][512] = (_Float16)x_s[tid][tn];
            hbuf16[wb][tid][513] = (_Float16)1.f;
        }
        __syncthreads();
    }

    // Epilogue: final h is in hbuf16[0] (t=255 wrote wb=0).
    if (tid < NB * NCLS) {
        const int c = tid / NCLS, cls = tid - c * NCLS;
        float s = bp[cls];
        for (int k = 0; k < HID; k++)
            s = fmaf(wph[cls * HID + k], (float)hbuf16[0][c][k], s);
        out[(b0 + c) * NCLS + cls] = s;
    }
}

extern "C" void kernel_launch(void* const* d_in, const int* in_sizes, int n_in,
                              void* d_out, int out_size, void* d_ws, size_t ws_size,
                              hipStream_t stream)
{
    const float* x   = (const float*)d_in[0];
    const float* wgx = (const float*)d_in[1];
    const float* wix = (const float*)d_in[2];
    const float* wfx = (const float*)d_in[3];
    const float* wox = (const float*)d_in[4];
    const float* wgh = (const float*)d_in[5];
    const float* wih = (const float*)d_in[6];
    const float* wfh = (const float*)d_in[7];
    const float* woh = (const float*)d_in[8];
    const float* bg  = (const float*)d_in[9];
    const float* bi  = (const float*)d_in[10];
    const float* bf  = (const float*)d_in[11];
    const float* bo  = (const float*)d_in[12];
    const float* wph = (const float*)d_in[13];
    const float* bp  = (const float*)d_in[14];
    const float* h0  = (const float*)d_in[15];
    const float* c0  = (const float*)d_in[16];
    float* out = (float*)d_out;

    char* ws = (char*)d_ws;
    f16x8*    wq16  = (f16x8*)ws;                    // [0, 512K)
    unsigned* seedw = (unsigned*)(ws + (512u << 10)); // [512K, 520K)
    uint2*    wq8   = (uint2*)(ws + (1u << 20));      // [1M, 1M+768K)

    pack16<<<dim3(137), dim3(256), 0, stream>>>(wgh, wgx, wix, wfx, wox,
                                                bg, bi, bf, bo, wq16, seedw);
    pack8<<<dim3(384), dim3(256), 0, stream>>>(wih, wfh, woh, wq8);
    lstm_mfma<<<dim3(BATCH / NB), dim3(512), 0, stream>>>(
        x, wq16, seedw, (const i64*)wq8, wph, bp, h0, c0, out);
}

// Round 7
// 2983.094 us; speedup vs baseline: 2.2166x; 1.6533x over previous
//
#include <hip/hip_runtime.h>
#include <math.h>

#define HID   512
#define SEQL  256
#define BATCH 2048
#define NCLS  10
#define NB    16     // batch columns per WG = full MFMA tile width
#define H8S   552    // bytes per fp8 h row in LDS (512 used; 8B-mult, bank-spread)

typedef _Float16 f16x8 __attribute__((ext_vector_type(8)));
typedef _Float16 f16x4 __attribute__((ext_vector_type(4)));
typedef _Float16 f16x2 __attribute__((ext_vector_type(2)));
typedef float    f32x4 __attribute__((ext_vector_type(4)));
typedef long     i64;
typedef long     i64x2 __attribute__((ext_vector_type(2)));

__device__ __forceinline__ float fsig(float v)  { return 1.f / (1.f + __expf(-v)); }
__device__ __forceinline__ float ftanh(float v) { return 1.f - 2.f / (1.f + __expf(2.f * v)); }

// ---- pack ALL 4 gates' recurrent weights as fp8 chunk-PAIR fragments -----
// wqn[((wv*8+mp)*16 + tile)*64 + lane] : uint4 (16B) = A-frags for row-tile
// p = wv+8*pi, gate gt (tile = gt*4+pi), chunks m0=2mp (bytes 0-7) and
// m1=2mp+1 (bytes 8-15).  byte v: fp8( w_gt[16p+(l&15)][(2mp+(v>>3))*32
// + (l>>4)*8 + (v&7)] * 128 ).  One dwordx4 load == TWO MFMA A-operands.
// seedw[gt*512 + p*16 + r] : f16x2 {wx*16384, b*16384} (x/bias seed, f16 path).
__global__ void pack8n(const float* __restrict__ wg, const float* __restrict__ wi,
                       const float* __restrict__ wf, const float* __restrict__ wo,
                       const float* __restrict__ gx, const float* __restrict__ ix,
                       const float* __restrict__ fx, const float* __restrict__ ox,
                       const float* __restrict__ bgp, const float* __restrict__ bip,
                       const float* __restrict__ bfp, const float* __restrict__ bop,
                       uint4* __restrict__ wqn, unsigned* __restrict__ seedw)
{
    const int idx = blockIdx.x * 256 + threadIdx.x;
    if (idx < 65536) {
        const int lane = idx & 63, tile = (idx >> 6) & 15;
        const int mp = (idx >> 10) & 7, wv = idx >> 13;
        const int gt = tile >> 2, pi = tile & 3;
        const int j = 16 * (wv + 8 * pi) + (lane & 15);
        const float* w = (gt == 0) ? wg : (gt == 1) ? wi : (gt == 2) ? wf : wo;
        unsigned dw[4];
        #pragma unroll
        for (int d = 0; d < 4; d++) {
            float f[4];
            #pragma unroll
            for (int e = 0; e < 4; e++) {
                const int v = 4 * d + e;
                const int k = (2 * mp + (v >> 3)) * 32 + (lane >> 4) * 8 + (v & 7);
                f[e] = w[j * HID + k] * 128.f;
            }
            int pk = __builtin_amdgcn_cvt_pk_fp8_f32(f[0], f[1], 0, false);
            pk     = __builtin_amdgcn_cvt_pk_fp8_f32(f[2], f[3], pk, true);
            dw[d] = (unsigned)pk;
        }
        wqn[idx] = make_uint4(dw[0], dw[1], dw[2], dw[3]);
    } else if (idx < 65536 + 2048) {
        const int s = idx - 65536;
        const int r = s & 15, p = (s >> 4) & 31, gt = s >> 9;
        const int j = 16 * p + r;
        const float wx = (gt == 0 ? gx : gt == 1 ? ix : gt == 2 ? fx : ox)[j];
        const float bb = (gt == 0 ? bgp : gt == 1 ? bip : gt == 2 ? bfp : bop)[j];
        f16x2 pr; pr[0] = (_Float16)(wx * 16384.f); pr[1] = (_Float16)(bb * 16384.f);
        seedw[s] = __builtin_bit_cast(unsigned, pr);
    }
}

// ---- persistent all-fp8 MFMA LSTM -----------------------------------------
// 128 WGs x 512 thr (8 waves/CU). R4/R6 post-mortem: time tracks VMEM
// INSTRUCTION count (21.7 cyc/instr through the per-CU L1 path), not bytes.
// This version: 128 dwordx4 loads/wave/step (was 272) — each load feeds 2
// fp8 MFMAs. All gate accs carry preact*16384 (w*128, h*128); x/bias enter
// via an f16 seed MFMA (exact pow2 un-scale at nonlin). h kept as fp8 in
// LDS (double-buffered, 1 barrier/step); f16 copy stored only at t=255.
__global__ __launch_bounds__(512, 1) void lstm_mfma(
    const float* __restrict__ x,                                   // [B][SEQ]
    const i64x2* __restrict__ wq, const unsigned* __restrict__ seedw,
    const float* __restrict__ wph, const float* __restrict__ bp,   // [C][H], [C]
    const float* __restrict__ h_init, const float* __restrict__ c_init, // [H]
    float* __restrict__ out)                                       // [B][C]
{
    __shared__ __align__(8)  char     h8s[2][NB * H8S];   // 17.3 KB
    __shared__ float x_s[NB][SEQL + 1];                   // 16.4 KB
    __shared__ __align__(16) _Float16 hfin[NB][HID];      // 16 KB (final h only)

    const int tid  = threadIdx.x;
    const int lane = tid & 63;
    const int wv   = tid >> 6;
    const int col  = lane & 15;
    const int kq   = lane >> 4;
    const int b0   = blockIdx.x * NB;
    const int wbase = wv * 8192 + lane;   // i64x2 units: wave's fragment stream base

    for (int i = tid; i < NB * SEQL; i += 512)
        x_s[i >> 8][i & 255] = x[(b0 + (i >> 8)) * SEQL + (i & 255)];

    for (int i = tid; i < 2 * NB * H8S; i += 512) {
        const int b = i / (NB * H8S), k = (i % (NB * H8S)) % H8S;
        const float v = (b == 0 && k < HID) ? h_init[k] * 128.f : 0.f;
        const int pk = __builtin_amdgcn_cvt_pk_fp8_f32(v, 0.f, 0, false);
        ((char*)h8s)[i] = (char)(pk & 0xff);
    }

    const int j00 = 16 * wv + 4 * kq;     // pi adds 128
    f32x4 creg[4];
    #pragma unroll
    for (int pi = 0; pi < 4; pi++) creg[pi] = *(const f32x4*)&c_init[j00 + 128 * pi];

    unsigned sv[4][4];  // seed (wx,b)*16384 f16 pairs; only kq==0 lanes nonzero
    #pragma unroll
    for (int gt = 0; gt < 4; gt++)
        #pragma unroll
        for (int pi = 0; pi < 4; pi++)
            sv[gt][pi] = (kq == 0) ? seedw[gt * 512 + (wv + 8 * pi) * 16 + col] : 0u;

    __syncthreads();

    #pragma unroll 1
    for (int t = 0; t < SEQL; t++) {
        const int rb = t & 1, wb = rb ^ 1;

        // Seed MFMA initializes acc: B cols k=0 (x_t), k=1 (1); A = (wx,b)*16384.
        f16x8 Bs = {};
        if (kq == 0) { Bs[0] = (_Float16)x_s[col][t]; Bs[1] = (_Float16)1.f; }
        f32x4 acc[16];  // tile = gt*4+pi, all indices compile-time below
        #pragma unroll
        for (int gt = 0; gt < 4; gt++)
            #pragma unroll
            for (int pi = 0; pi < 4; pi++) {
                const f16x2 pr = __builtin_bit_cast(f16x2, sv[gt][pi]);
                f16x8 F = {};
                F[0] = pr[0]; F[1] = pr[1];
                acc[gt * 4 + pi] = __builtin_amdgcn_mfma_f32_16x16x32_f16(
                    F, Bs, (f32x4){0.f, 0.f, 0.f, 0.f}, 0, 0, 0);
            }

        // K-loop: 8 chunk-pairs; per pair 16 dwordx4 loads (two 8-load halves,
        // PA = tiles 0-7 (gates g,i), PB = tiles 8-15 (gates f,o)), 32 MFMAs.
        i64x2 PA[8], PB[8];
        #pragma unroll
        for (int i = 0; i < 8; i++) PA[i] = wq[wbase + i * 64];   // mp=0 half 0

        #pragma unroll 1
        for (int mp = 0; mp < 8; mp++) {
            const i64 Bm0 = *(const i64*)&h8s[rb][col * H8S + (2 * mp) * 32 + kq * 8];
            const i64 Bm1 = *(const i64*)&h8s[rb][col * H8S + (2 * mp + 1) * 32 + kq * 8];
            #pragma unroll
            for (int i = 0; i < 8; i++) PB[i] = wq[wbase + (mp * 16 + 8 + i) * 64];
            #pragma unroll
            for (int i = 0; i < 8; i++) {
                acc[i] = __builtin_amdgcn_mfma_f32_16x16x32_fp8_fp8(PA[i].x, Bm0, acc[i], 0, 0, 0);
                acc[i] = __builtin_amdgcn_mfma_f32_16x16x32_fp8_fp8(PA[i].y, Bm1, acc[i], 0, 0, 0);
            }
            const int mpn = (mp < 7) ? mp + 1 : 7;
            #pragma unroll
            for (int i = 0; i < 8; i++) PA[i] = wq[wbase + (mpn * 16 + i) * 64];
            #pragma unroll
            for (int i = 0; i < 8; i++) {
                acc[8 + i] = __builtin_amdgcn_mfma_f32_16x16x32_fp8_fp8(PB[i].x, Bm0, acc[8 + i], 0, 0, 0);
                acc[8 + i] = __builtin_amdgcn_mfma_f32_16x16x32_fp8_fp8(PB[i].y, Bm1, acc[8 + i], 0, 0, 0);
            }
        }

        // Nonlinearity: accs hold preact*16384; one exact pow2 un-scale.
        const float S2I = 1.f / 16384.f;
        #pragma unroll
        for (int pi = 0; pi < 4; pi++) {
            const int j0 = j00 + 128 * pi;
            float hr[4];
            #pragma unroll
            for (int r = 0; r < 4; r++) {
                const float g  = ftanh(acc[pi][r] * S2I);
                const float ii = fsig(acc[4 + pi][r] * S2I);
                const float ff = fsig(acc[8 + pi][r] * S2I);
                const float oo = fsig(acc[12 + pi][r] * S2I);
                const float cc = fmaf(g, ii, creg[pi][r] * ff);
                creg[pi][r] = cc;
                hr[r] = ftanh(cc) * oo;
            }
            int pk = __builtin_amdgcn_cvt_pk_fp8_f32(hr[0] * 128.f, hr[1] * 128.f, 0, false);
            pk     = __builtin_amdgcn_cvt_pk_fp8_f32(hr[2] * 128.f, hr[3] * 128.f, pk, true);
            *(unsigned*)&h8s[wb][col * H8S + j0] = (unsigned)pk;
            if (t == SEQL - 1) {
                f16x4 hv;
                #pragma unroll
                for (int r = 0; r < 4; r++) hv[r] = (_Float16)hr[r];
                *(f16x4*)&hfin[col][j0] = hv;
            }
        }
        __syncthreads();
    }

    // Epilogue: out[b][cls] = bp[cls] + sum_k wph[cls][k] * h_final[k][b]
    if (tid < NB * NCLS) {
        const int c = tid / NCLS, cls = tid - c * NCLS;
        float s = bp[cls];
        for (int k = 0; k < HID; k++)
            s = fmaf(wph[cls * HID + k], (float)hfin[c][k], s);
        out[(b0 + c) * NCLS + cls] = s;
    }
}

extern "C" void kernel_launch(void* const* d_in, const int* in_sizes, int n_in,
                              void* d_out, int out_size, void* d_ws, size_t ws_size,
                              hipStream_t stream)
{
    const float* x   = (const float*)d_in[0];
    const float* wgx = (const float*)d_in[1];
    const float* wix = (const float*)d_in[2];
    const float* wfx = (const float*)d_in[3];
    const float* wox = (const float*)d_in[4];
    const float* wgh = (const float*)d_in[5];
    const float* wih = (const float*)d_in[6];
    const float* wfh = (const float*)d_in[7];
    const float* woh = (const float*)d_in[8];
    const float* bg  = (const float*)d_in[9];
    const float* bi  = (const float*)d_in[10];
    const float* bf  = (const float*)d_in[11];
    const float* bo  = (const float*)d_in[12];
    const float* wph = (const float*)d_in[13];
    const float* bp  = (const float*)d_in[14];
    const float* h0  = (const float*)d_in[15];
    const float* c0  = (const float*)d_in[16];
    float* out = (float*)d_out;

    char* ws = (char*)d_ws;
    uint4*    wqn   = (uint4*)ws;                     // [0, 1M): fp8 pair fragments
    unsigned* seedw = (unsigned*)(ws + (1u << 20));   // [1M, 1M+8K)

    pack8n<<<dim3(264), dim3(256), 0, stream>>>(wgh, wih, wfh, woh,
                                                wgx, wix, wfx, wox,
                                                bg, bi, bf, bo, wqn, seedw);
    lstm_mfma<<<dim3(BATCH / NB), dim3(512), 0, stream>>>(
        x, (const i64x2*)wqn, seedw, wph, bp, h0, c0, out);
}